// Round 3
// baseline (319.489 us; speedup 1.0000x reference)
//
#include <hip/hip_runtime.h>

// B=8, S=256, C=256, V=64 — fp32 in/out, split-fp16 MFMA internally.
// out[b,s,z,k] = tanh( BIL + r[b,z,k] + t[b,s,k] )
//   W_eff[i,j,k] = W[i,j,k] + (i==j)*linmul_w[k,j]    (split: wt_hi+wt_lo, n'=k*256+j)
//   ctx split: ch_hi + ch_lo (exact fp16 pair)
//   tmp[(b,s)][k][j] = ctx ⊗ W_eff   (GEMM1: Ah·Bh + Al·Bh + Ah·Bl, fp32 acc, fp16 store)
//   BIL = ctx ⊗ tmp                  (GEMM2: Ah·B + Al·B)
//   residual error ≈ tmp-fp16 rounding only → absmax ~0.01

typedef __attribute__((ext_vector_type(8))) _Float16 half8;
typedef __attribute__((ext_vector_type(4))) _Float16 half4v;
typedef __attribute__((ext_vector_type(4))) float f32x4;

__device__ __forceinline__ void async16(const void* g, void* l) {
  __builtin_amdgcn_global_load_lds(
      (__attribute__((address_space(1))) void*)g,
      (__attribute__((address_space(3))) void*)l, 16, 0, 0);
}

// ---- prep A: r/t vectors + ctx hi/lo split ----
__global__ __launch_bounds__(256) void prep_rt(
    const float* __restrict__ ctx, const float* __restrict__ bias,
    const float* __restrict__ l1w, const float* __restrict__ l1b,
    const float* __restrict__ l2w, const float* __restrict__ l2b,
    const float* __restrict__ lmb, const float* __restrict__ ldw,
    const float* __restrict__ ldb, float* __restrict__ rbuf,
    float* __restrict__ tbuf, _Float16* __restrict__ ch_hi,
    _Float16* __restrict__ ch_lo) {
  __shared__ float Cs[4 * 256];
  const int t = threadIdx.x;
  const int row0 = blockIdx.x * 4;
  float4 v = ((const float4*)(ctx + (size_t)row0 * 256))[t];
  ((float4*)Cs)[t] = v;
  // ctx hi/lo split (exact pair): 4 elems per thread
  {
    float xs[4] = {v.x, v.y, v.z, v.w};
    half4v h, l;
#pragma unroll
    for (int e = 0; e < 4; ++e) {
      _Float16 hh = (_Float16)xs[e];
      h[e] = hh;
      l[e] = (_Float16)(xs[e] - (float)hh);
    }
    *(half4v*)&ch_hi[(size_t)row0 * 256 + t * 4] = h;
    *(half4v*)&ch_lo[(size_t)row0 * 256 + t * 4] = l;
  }
  __syncthreads();
  const int k = t & 63, lr = t >> 6;
  const float* l1r = l1w + k * 256;
  const float* l2r = l2w + k * 256;
  const float* ldr = ldw + k * 256;
  float a1 = 0.f, a2 = 0.f;
  for (int c = 0; c < 256; c += 4) {
    float4 w1 = *(const float4*)(l1r + c);
    float4 w2 = *(const float4*)(l2r + c);
    float4 wd = *(const float4*)(ldr + c);
    float4 cv = *(const float4*)(&Cs[lr * 256 + c]);
    a1 += cv.x * (w1.x + wd.x) + cv.y * (w1.y + wd.y) +
          cv.z * (w1.z + wd.z) + cv.w * (w1.w + wd.w);
    a2 += cv.x * (w2.x - wd.x) + cv.y * (w2.y - wd.y) +
          cv.z * (w2.z - wd.z) + cv.w * (w2.w - wd.w);
  }
  int row = row0 + lr;
  rbuf[row * 64 + k] = a1 + l1b[k];
  tbuf[row * 64 + k] = a2 + l2b[k] + bias[k] + lmb[k] + ldb[k];
}

// ---- prep B: wt_{hi,lo}[n'=(k*256+j)][i] = split( W[i][j][k] + (i==j)*lmw[k*256+j] ) ----
__global__ __launch_bounds__(256) void prep_wt(const float* __restrict__ W,
                                               const float* __restrict__ lmw,
                                               _Float16* __restrict__ wt_hi,
                                               _Float16* __restrict__ wt_lo) {
  __shared__ float T[256 * 68];  // [i][k] fp32, pad 64->68
  const int t = threadIdx.x;
  const int j = blockIdx.x;
#pragma unroll
  for (int p = 0; p < 16; ++p) {
    int i = p * 16 + (t >> 4);
    int c = t & 15;
    float4 v = *(const float4*)&W[(size_t)i * 16384 + j * 64 + c * 4];
    if (i == j) {
      v.x += lmw[(c * 4 + 0) * 256 + j];
      v.y += lmw[(c * 4 + 1) * 256 + j];
      v.z += lmw[(c * 4 + 2) * 256 + j];
      v.w += lmw[(c * 4 + 3) * 256 + j];
    }
    *(float4*)&T[i * 68 + c * 4] = v;
  }
  __syncthreads();
  const int k = t >> 2, i0 = (t & 3) * 64;
  _Float16* dh = wt_hi + ((size_t)(k * 256 + j)) * 256 + i0;
  _Float16* dl = wt_lo + ((size_t)(k * 256 + j)) * 256 + i0;
#pragma unroll
  for (int u = 0; u < 64; u += 8) {
    half8 h, l;
#pragma unroll
    for (int e = 0; e < 8; ++e) {
      float x = T[(i0 + u + e) * 68 + k];
      _Float16 hh = (_Float16)x;
      h[e] = hh;
      l[e] = (_Float16)(x - (float)hh);
    }
    *(half8*)(dh + u) = h;
    *(half8*)(dl + u) = l;
  }
}

// ---- GEMM1: tmp[m][n'] (M=2048,N=16384,K=256), 3-pass split fp16 ----
__global__ __launch_bounds__(256) void gemm1(const _Float16* __restrict__ ahp,
                                             const _Float16* __restrict__ alp,
                                             const _Float16* __restrict__ bhp,
                                             const _Float16* __restrict__ blp,
                                             _Float16* __restrict__ tmp) {
  __shared__ _Float16 Ah[128 * 32];
  __shared__ _Float16 Al[128 * 32];
  __shared__ _Float16 Bs[128 * 32];
  const int t = threadIdx.x;
  const int lane = t & 63, wave = t >> 6;
  const int m0 = blockIdx.y * 128, n0 = blockIdx.x * 128;
  const int wm = (wave & 1) * 64, wn = (wave >> 1) * 64;
  const int r = lane & 15, q = lane >> 4;
  f32x4 acc[4][4] = {};
  const int row = t >> 2, seg = (t & 3) * 8;
  const _Float16* gAh = ahp + (size_t)(m0 + row) * 256 + seg;
  const _Float16* gAl = alp + (size_t)(m0 + row) * 256 + seg;
  const _Float16* gBh = bhp + (size_t)(n0 + row) * 256 + seg;
  const _Float16* gBl = blp + (size_t)(n0 + row) * 256 + seg;
  // phase 1: (Ah + Al) · Bh
  for (int k0 = 0; k0 < 256; k0 += 32) {
    async16(gAh + k0, &Ah[t * 8]);
    async16(gAh + 64 * 256 + k0, &Ah[2048 + t * 8]);
    async16(gAl + k0, &Al[t * 8]);
    async16(gAl + 64 * 256 + k0, &Al[2048 + t * 8]);
    async16(gBh + k0, &Bs[t * 8]);
    async16(gBh + 64 * 256 + k0, &Bs[2048 + t * 8]);
    __syncthreads();
    half8 a[4], c[4], b[4];
#pragma unroll
    for (int mi = 0; mi < 4; ++mi) {
      a[mi] = *(const half8*)&Ah[(wm + mi * 16 + r) * 32 + q * 8];
      c[mi] = *(const half8*)&Al[(wm + mi * 16 + r) * 32 + q * 8];
    }
#pragma unroll
    for (int ni = 0; ni < 4; ++ni)
      b[ni] = *(const half8*)&Bs[(wn + ni * 16 + r) * 32 + q * 8];
#pragma unroll
    for (int mi = 0; mi < 4; ++mi)
#pragma unroll
      for (int ni = 0; ni < 4; ++ni) {
        acc[mi][ni] = __builtin_amdgcn_mfma_f32_16x16x32_f16(a[mi], b[ni],
                                                             acc[mi][ni], 0, 0, 0);
        acc[mi][ni] = __builtin_amdgcn_mfma_f32_16x16x32_f16(c[mi], b[ni],
                                                             acc[mi][ni], 0, 0, 0);
      }
    __syncthreads();
  }
  // phase 2: Ah · Bl
  for (int k0 = 0; k0 < 256; k0 += 32) {
    async16(gAh + k0, &Ah[t * 8]);
    async16(gAh + 64 * 256 + k0, &Ah[2048 + t * 8]);
    async16(gBl + k0, &Bs[t * 8]);
    async16(gBl + 64 * 256 + k0, &Bs[2048 + t * 8]);
    __syncthreads();
    half8 a[4], b[4];
#pragma unroll
    for (int mi = 0; mi < 4; ++mi)
      a[mi] = *(const half8*)&Ah[(wm + mi * 16 + r) * 32 + q * 8];
#pragma unroll
    for (int ni = 0; ni < 4; ++ni)
      b[ni] = *(const half8*)&Bs[(wn + ni * 16 + r) * 32 + q * 8];
#pragma unroll
    for (int mi = 0; mi < 4; ++mi)
#pragma unroll
      for (int ni = 0; ni < 4; ++ni)
        acc[mi][ni] = __builtin_amdgcn_mfma_f32_16x16x32_f16(a[mi], b[ni],
                                                             acc[mi][ni], 0, 0, 0);
    __syncthreads();
  }
#pragma unroll
  for (int mi = 0; mi < 4; ++mi)
#pragma unroll
    for (int ni = 0; ni < 4; ++ni) {
      int m = m0 + wm + mi * 16 + q * 4;
      int n = n0 + wn + ni * 16 + r;
#pragma unroll
      for (int e = 0; e < 4; ++e)
        tmp[(size_t)(m + e) * 16384 + n] = (_Float16)acc[mi][ni][e];
    }
}

// ---- GEMM2 + epilogue: block = (b, s-quad, 128x128 subtile) ----
// M = z (256), N = (s_local,k) (256); B rows are consecutive tmp rows.
__global__ __launch_bounds__(256) void gemm2(const _Float16* __restrict__ ahp,
                                             const _Float16* __restrict__ alp,
                                             const _Float16* __restrict__ tmp,
                                             const float* __restrict__ rbuf,
                                             const float* __restrict__ tbuf,
                                             float* __restrict__ out) {
  __shared__ _Float16 Ah[128 * 32];
  __shared__ _Float16 Al[128 * 32];
  __shared__ _Float16 Bs[128 * 32];
  const int t = threadIdx.x;
  const int lane = t & 63, wave = t >> 6;
  const int gx = blockIdx.x;
  const int bq = gx >> 2, mt = (gx >> 1) & 1, nt = gx & 1;
  const int b = bq >> 6, s0 = (bq & 63) * 4;
  const int wm = (wave & 1) * 64, wn = (wave >> 1) * 64;
  const int r = lane & 15, q = lane >> 4;
  f32x4 acc[4][4] = {};
  const int row = t >> 2, seg = (t & 3) * 8;
  const _Float16* gAh = ahp + ((size_t)b * 256 + mt * 128 + row) * 256 + seg;
  const _Float16* gAl = alp + ((size_t)b * 256 + mt * 128 + row) * 256 + seg;
  const _Float16* gB =
      tmp + ((size_t)(b * 256 + s0) * 64 + nt * 128 + row) * 256 + seg;
  for (int j0 = 0; j0 < 256; j0 += 32) {
    async16(gAh + j0, &Ah[t * 8]);
    async16(gAh + 64 * 256 + j0, &Ah[2048 + t * 8]);
    async16(gAl + j0, &Al[t * 8]);
    async16(gAl + 64 * 256 + j0, &Al[2048 + t * 8]);
    async16(gB + j0, &Bs[t * 8]);
    async16(gB + 64 * 256 + j0, &Bs[2048 + t * 8]);
    __syncthreads();
    half8 a[4], c[4], bfr[4];
#pragma unroll
    for (int mi = 0; mi < 4; ++mi) {
      a[mi] = *(const half8*)&Ah[(wm + mi * 16 + r) * 32 + q * 8];
      c[mi] = *(const half8*)&Al[(wm + mi * 16 + r) * 32 + q * 8];
    }
#pragma unroll
    for (int ni = 0; ni < 4; ++ni)
      bfr[ni] = *(const half8*)&Bs[(wn + ni * 16 + r) * 32 + q * 8];
#pragma unroll
    for (int mi = 0; mi < 4; ++mi)
#pragma unroll
      for (int ni = 0; ni < 4; ++ni) {
        acc[mi][ni] = __builtin_amdgcn_mfma_f32_16x16x32_f16(a[mi], bfr[ni],
                                                             acc[mi][ni], 0, 0, 0);
        acc[mi][ni] = __builtin_amdgcn_mfma_f32_16x16x32_f16(c[mi], bfr[ni],
                                                             acc[mi][ni], 0, 0, 0);
      }
    __syncthreads();
  }
#pragma unroll
  for (int mi = 0; mi < 4; ++mi)
#pragma unroll
    for (int ni = 0; ni < 4; ++ni) {
      int z0 = mt * 128 + wm + mi * 16 + q * 4;
      int n = nt * 128 + wn + ni * 16 + r;
      int s_l = n >> 6, k = n & 63;
      const float tk = tbuf[(b * 256 + s0 + s_l) * 64 + k];
#pragma unroll
      for (int e = 0; e < 4; ++e) {
        int z = z0 + e;
        float x = acc[mi][ni][e] + rbuf[(size_t)b * 16384 + z * 64 + k] + tk;
        float ax = fabsf(x);
        float ev = __expf(-2.0f * ax);
        float y = (1.0f - ev) / (1.0f + ev);
        y = copysignf(y, x);
        out[(((size_t)b * 256 + s0 + s_l) * 256 + z) * 64 + k] = y;
      }
    }
}

extern "C" void kernel_launch(void* const* d_in, const int* in_sizes, int n_in,
                              void* d_out, int out_size, void* d_ws, size_t ws_size,
                              hipStream_t stream) {
  const float* ctx  = (const float*)d_in[0];
  const float* W    = (const float*)d_in[1];
  const float* bias = (const float*)d_in[2];
  const float* l1w  = (const float*)d_in[3];
  const float* l1b  = (const float*)d_in[4];
  const float* l2w  = (const float*)d_in[5];
  const float* l2b  = (const float*)d_in[6];
  const float* lmw  = (const float*)d_in[7];
  const float* lmb  = (const float*)d_in[8];
  const float* ldw  = (const float*)d_in[9];
  const float* ldb  = (const float*)d_in[10];
  float* out = (float*)d_out;

  char* ws = (char*)d_ws;
  _Float16* ch_hi = (_Float16*)ws;                         // 1 MiB
  _Float16* ch_lo = (_Float16*)(ws + (1u << 20));          // 1 MiB
  _Float16* wt_hi = (_Float16*)(ws + (2u << 20));          // 8 MiB
  _Float16* wt_lo = (_Float16*)(ws + (10u << 20));         // 8 MiB
  _Float16* tmp   = (_Float16*)(ws + (18u << 20));         // 64 MiB
  float* rbuf = (float*)(ws + (82u << 20));                // 512 KiB
  float* tbuf = rbuf + 2048 * 64;                          // 512 KiB

  prep_rt<<<512, 256, 0, stream>>>(ctx, bias, l1w, l1b, l2w, l2b, lmb, ldw, ldb,
                                   rbuf, tbuf, ch_hi, ch_lo);
  prep_wt<<<256, 256, 0, stream>>>(W, lmw, wt_hi, wt_lo);
  gemm1<<<dim3(128, 16), 256, 0, stream>>>(ch_hi, ch_lo, wt_hi, wt_lo, tmp);
  gemm2<<<2048, 256, 0, stream>>>(ch_hi, ch_lo, tmp, rbuf, tbuf, out);
}